// Round 14
// baseline (17124.223 us; speedup 1.0000x reference)
//
#include <hip/hip_runtime.h>
#include <hip/hip_bf16.h>

// v14 = v12's exchange (8-replica tagged h, poll2, append-only y0 log,
// no fences/flags) + v8's LDS-resident bf16 weights for phase A
// (conflict-free per-wave-row pattern, verified 0 conflicts in R8).
// 192 WGs: 64 L0 x 16 units, 128 L1 x 8 units. Weights converted f2bf
// inline at WG startup (48 rows -> 96KB LDS per WG).

#define TT    4096
#define HDIM  1024
#define L0WG  64
#define L1WG  128
#define SBS   512
#define NREP  8
typedef unsigned short ushort_t;
typedef unsigned long long u64;

// ---------------- embedding gather ----------------
__global__ void embed_kernel(const int* __restrict__ idx,
                             const float* __restrict__ emb,
                             float* __restrict__ x) {
    int t = blockIdx.x;
    int row = idx[t];
    const float4* src = reinterpret_cast<const float4*>(emb + (size_t)row * HDIM);
    float4* dst = reinterpret_cast<float4*>(x + (size_t)t * HDIM);
    dst[threadIdx.x] = src[threadIdx.x];
}

// ---------------- fp32 NT GEMM (gi0) ----------------
#define BM 64
#define BN 64
#define BK 32
__global__ __launch_bounds__(256)
void gemm_nt_bias(const float* __restrict__ A,
                  const float* __restrict__ Bw,
                  const float* __restrict__ bias,
                  float* __restrict__ C,
                  int M, int N, int K) {
    __shared__ float As[BK][BM];
    __shared__ float Bs[BK][BN];
    const int tid = threadIdx.x;
    const int m0 = blockIdx.x * BM;
    const int n0 = blockIdx.y * BN;
    const int tx = tid & 15, ty = tid >> 4;
    const int lr = tid >> 3;
    const int lc = (tid & 7) * 4;

    float acc[4][4] = {};

    for (int k0 = 0; k0 < K; k0 += BK) {
#pragma unroll
        for (int pass = 0; pass < 2; ++pass) {
            int m = lr + pass * 32;
            float4 v = *reinterpret_cast<const float4*>(A + (size_t)(m0 + m) * K + k0 + lc);
            As[lc + 0][m] = v.x; As[lc + 1][m] = v.y;
            As[lc + 2][m] = v.z; As[lc + 3][m] = v.w;
            float4 u = *reinterpret_cast<const float4*>(Bw + (size_t)(n0 + m) * K + k0 + lc);
            Bs[lc + 0][m] = u.x; Bs[lc + 1][m] = u.y;
            Bs[lc + 2][m] = u.z; Bs[lc + 3][m] = u.w;
        }
        __syncthreads();
#pragma unroll
        for (int kk = 0; kk < BK; ++kk) {
            float4 a = *reinterpret_cast<const float4*>(&As[kk][ty * 4]);
            float4 b = *reinterpret_cast<const float4*>(&Bs[kk][tx * 4]);
            float av[4] = {a.x, a.y, a.z, a.w};
            float bv[4] = {b.x, b.y, b.z, b.w};
#pragma unroll
            for (int i = 0; i < 4; ++i)
#pragma unroll
                for (int j = 0; j < 4; ++j)
                    acc[i][j] = fmaf(av[i], bv[j], acc[i][j]);
        }
        __syncthreads();
    }

    float4 b4 = *reinterpret_cast<const float4*>(bias + n0 + tx * 4);
    float bb[4] = {b4.x, b4.y, b4.z, b4.w};
#pragma unroll
    for (int i = 0; i < 4; ++i) {
        int m = m0 + ty * 4 + i;
        float4 o;
        o.x = acc[i][0] + bb[0];
        o.y = acc[i][1] + bb[1];
        o.z = acc[i][2] + bb[2];
        o.w = acc[i][3] + bb[3];
        *reinterpret_cast<float4*>(C + (size_t)m * N + n0 + tx * 4) = o;
    }
}

// ---------------- helpers ----------------
__device__ __forceinline__ float fsig(float x) { return 1.f / (1.f + __expf(-x)); }
__device__ __forceinline__ float ftanh(float x) {
    return fmaf(-2.f, 1.f / (1.f + __expf(2.f * x)), 1.f);
}
__device__ __forceinline__ float bflo(unsigned u) { return __uint_as_float(u << 16); }
__device__ __forceinline__ float bfhi(unsigned u) { return __uint_as_float(u & 0xffff0000u); }
__device__ __forceinline__ ushort_t f2bf(float f) {
    unsigned u = __float_as_uint(f);
    return (ushort_t)((u + 0x7FFFu + ((u >> 16) & 1u)) >> 16);
}
__device__ __forceinline__ u64 pack_h(unsigned seq, float h) {
    return ((u64)seq << 32) | (u64)__float_as_uint(h);
}
__device__ __forceinline__ u64 aload(const u64* p) {
    return __hip_atomic_load(p, __ATOMIC_RELAXED, __HIP_MEMORY_SCOPE_AGENT);
}
__device__ __forceinline__ u64 poll_h(const u64* p, unsigned need) {
    u64 v = aload(p);
    while ((unsigned)(v >> 32) < need) v = aload(p);
    return v;
}
__device__ __forceinline__ void poll2(const u64* p0, const u64* p1, unsigned need,
                                      u64& v0, u64& v1) {
    v0 = aload(p0);
    v1 = aload(p1);
    while ((unsigned)(v0 >> 32) < need || (unsigned)(v1 >> 32) < need) {
        v0 = aload(p0);
        v1 = aload(p1);
    }
}
__device__ __forceinline__ void pub_h(u64* rep, int par, int idx, u64 v) {
#pragma unroll
    for (int r = 0; r < NREP; ++r)
        __hip_atomic_store(rep + ((size_t)r * 2 + par) * HDIM + idx, v,
                           __ATOMIC_RELAXED, __HIP_MEMORY_SCOPE_AGENT);
}
__device__ __forceinline__ float dot_bf16(uint2 w0, uint2 w1, uint2 w2, uint2 w3,
                                          float4 hA, float4 hB, float4 hC, float4 hD) {
    float p = 0.f;
    p = fmaf(bflo(w0.x), hA.x, p); p = fmaf(bfhi(w0.x), hA.y, p);
    p = fmaf(bflo(w0.y), hA.z, p); p = fmaf(bfhi(w0.y), hA.w, p);
    p = fmaf(bflo(w1.x), hB.x, p); p = fmaf(bfhi(w1.x), hB.y, p);
    p = fmaf(bflo(w1.y), hB.z, p); p = fmaf(bfhi(w1.y), hB.w, p);
    p = fmaf(bflo(w2.x), hC.x, p); p = fmaf(bfhi(w2.x), hC.y, p);
    p = fmaf(bflo(w2.y), hC.z, p); p = fmaf(bfhi(w2.y), hC.w, p);
    p = fmaf(bflo(w3.x), hD.x, p); p = fmaf(bfhi(w3.x), hD.y, p);
    p = fmaf(bflo(w3.y), hD.z, p); p = fmaf(bfhi(w3.y), hD.w, p);
    return p;
}
// one per-wave row dot: row in lds_w, input vec in lds (float4 view)
__device__ __forceinline__ void row_dot(const uint2* wr, const float4* v4,
                                        int ln, float* dst, int row) {
    float4 hA = v4[ln], hB = v4[64 + ln], hC = v4[128 + ln], hD = v4[192 + ln];
    float p = dot_bf16(wr[ln], wr[64 + ln], wr[128 + ln], wr[192 + ln],
                       hA, hB, hC, hD);
    p += __shfl_xor(p, 1);  p += __shfl_xor(p, 2);
    p += __shfl_xor(p, 4);  p += __shfl_xor(p, 8);
    p += __shfl_xor(p, 16); p += __shfl_xor(p, 32);
    if (ln == 0) dst[row] = p;
}

// ---------------- fused pipelined scan v14 ----------------
__global__ __launch_bounds__(SBS, 1)
void gru_pipe(const float* __restrict__ gi0,
              const float* __restrict__ whh0,
              const float* __restrict__ bhh0,
              const float* __restrict__ wih1,
              const float* __restrict__ whh1,
              const float* __restrict__ bih1,
              const float* __restrict__ bhh1,
              u64* y0log,                  // [T][HDIM] tagged, append-only
              float* __restrict__ out,     // [T*H + 2H]
              u64* h0rep, u64* h1rep) {    // [NREP][2][HDIM] tagged
    const int tid = threadIdx.x;
    const int wv  = tid >> 6;
    const int ln  = tid & 63;
    const int xcd = blockIdx.x & 7;

    __shared__ __align__(16) ushort_t lds_w[48 * HDIM];   // 96KB
    __shared__ __align__(16) float lds_h[HDIM];
    __shared__ __align__(16) float lds_y[2][HDIM];
    __shared__ float lds_gh[48];
    __shared__ float lds_gi[2][48];

    if (blockIdx.x < L0WG) {
        // ================= layer 0 (16 units/WG) =================
        const int g = blockIdx.x;
        const int u0 = g * 16;

        // 48 whh rows -> bf16 LDS
        for (int i = tid; i < 48 * 512; i += SBS) {
            const int r = i >> 9, c = i & 511;
            const size_t grow = (size_t)((r >> 4) * HDIM + u0 + (r & 15)) * HDIM;
            const float2 a = *reinterpret_cast<const float2*>(whh0 + grow + 2 * c);
            reinterpret_cast<unsigned*>(lds_w)[r * 512 + c] =
                (unsigned)f2bf(a.x) | ((unsigned)f2bf(a.y) << 16);
        }

        float bh0 = 0.f, bh1 = 0.f, bh2 = 0.f;
        float gir = 0.f, giz = 0.f, gin = 0.f;
        float h_own = 0.f;
        if (tid < 16) {
            const int gj = u0 + tid;
            bh0 = bhh0[0 * HDIM + gj];
            bh1 = bhh0[1 * HDIM + gj];
            bh2 = bhh0[2 * HDIM + gj];
            gir = gi0[gj];
            giz = gi0[HDIM + gj];
            gin = gi0[2 * HDIM + gj];
        }

        lds_h[tid] = 0.f;
        lds_h[tid + SBS] = 0.f;
        __syncthreads();

        const float4* lh4 = reinterpret_cast<const float4*>(lds_h);
        const uint2* w2 = reinterpret_cast<const uint2*>(lds_w);

        for (int t = 0; t < TT; ++t) {
            float nir = 0.f, niz = 0.f, nin = 0.f;
            if (tid < 16 && t + 1 < TT) {
                const float* base = gi0 + (size_t)(t + 1) * 3 * HDIM + u0 + tid;
                nir = base[0];
                niz = base[HDIM];
                nin = base[2 * HDIM];
            }

            // phase A: 6 waves x 8 rows
            if (wv < 6) {
#pragma unroll
                for (int rr = 0; rr < 8; ++rr) {
                    const int row = wv * 8 + rr;
                    row_dot(w2 + row * 256, lh4, ln, lds_gh, row);
                }
            }
            __syncthreads();   // S1

            if (tid < 16) {
                const int gj = u0 + tid;
                const float r = fsig(gir + lds_gh[tid]      + bh0);
                const float z = fsig(giz + lds_gh[16 + tid] + bh1);
                const float n = ftanh(gin + r * (lds_gh[32 + tid] + bh2));
                const float h_new = (1.f - z) * n + z * h_own;
                h_own = h_new;
                const u64 pk = pack_h((unsigned)(t + 1), h_new);
                pub_h(h0rep, (t + 1) & 1, gj, pk);
                __hip_atomic_store(y0log + (size_t)t * HDIM + gj, pk,
                                   __ATOMIC_RELAXED, __HIP_MEMORY_SCOPE_AGENT);
                if (t == TT - 1) out[(size_t)TT * HDIM + gj] = h_new;
            }

            {
                const unsigned need = (unsigned)(t + 1);
                const u64* hp = h0rep + ((size_t)xcd * 2 + ((t + 1) & 1)) * HDIM;
                u64 v0, v1;
                poll2(hp + 2 * tid, hp + 2 * tid + 1, need, v0, v1);
                float2 hv;
                hv.x = __uint_as_float((unsigned)v0);
                hv.y = __uint_as_float((unsigned)v1);
                reinterpret_cast<float2*>(lds_h)[tid] = hv;
            }
            gir = nir; giz = niz; gin = nin;
            __syncthreads();   // S2
        }
    } else {
        // ================= layer 1 (8 units/WG) =================
        const int g1 = blockIdx.x - L0WG;   // 0..127
        const int u0 = g1 * 8;

        // 24 whh rows (lds_w[0..23]) + 24 wih rows (lds_w[24..47]) -> bf16 LDS
        for (int i = tid; i < 24 * 512; i += SBS) {
            const int r = i >> 9, c = i & 511;
            const size_t grow = (size_t)((r >> 3) * HDIM + u0 + (r & 7)) * HDIM;
            const float2 a = *reinterpret_cast<const float2*>(whh1 + grow + 2 * c);
            reinterpret_cast<unsigned*>(lds_w)[r * 512 + c] =
                (unsigned)f2bf(a.x) | ((unsigned)f2bf(a.y) << 16);
            const float2 b = *reinterpret_cast<const float2*>(wih1 + grow + 2 * c);
            reinterpret_cast<unsigned*>(lds_w)[(24 + r) * 512 + c] =
                (unsigned)f2bf(b.x) | ((unsigned)f2bf(b.y) << 16);
        }

        float bh0 = 0.f, bh1 = 0.f, bh2 = 0.f;
        float bi0 = 0.f, bi1 = 0.f, bi2 = 0.f;
        float h_own = 0.f;
        if (tid < 8) {
            const int u = u0 + tid;
            bh0 = bhh1[0 * HDIM + u];
            bh1 = bhh1[1 * HDIM + u];
            bh2 = bhh1[2 * HDIM + u];
            bi0 = bih1[0 * HDIM + u];
            bi1 = bih1[1 * HDIM + u];
            bi2 = bih1[2 * HDIM + u];
        }

        lds_h[tid] = 0.f;
        lds_h[tid + SBS] = 0.f;

        // prologue: stage y(0), y(1) from log (all threads, 2 words each/step)
        __syncthreads();
#pragma unroll
        for (int s = 0; s < 2; ++s)
#pragma unroll
            for (int k = 0; k < 2; ++k) {
                u64 v = poll_h(y0log + (size_t)s * HDIM + k * 512 + tid, (unsigned)(s + 1));
                lds_y[s][k * 512 + tid] = __uint_as_float((unsigned)v);
            }
        __syncthreads();

        const float4* lh4 = reinterpret_cast<const float4*>(lds_h);
        const uint2* w2 = reinterpret_cast<const uint2*>(lds_w);

        // gi(0) from lds_y[0] (waves 3-5)
        if (wv >= 3 && wv < 6) {
            const float4* ly4 = reinterpret_cast<const float4*>(lds_y[0]);
#pragma unroll
            for (int rr = 0; rr < 8; ++rr) {
                const int row = (wv - 3) * 8 + rr;
                row_dot(w2 + (24 + row) * 256, ly4, ln, lds_gi[0], row);
            }
        }
        __syncthreads();

        for (int t = 0; t < TT; ++t) {
            // phase A: wv<3 whh.h | wv 3-5 gi(t+1) | wv>=6 stage y(t+2)
            if (wv < 3) {
#pragma unroll
                for (int rr = 0; rr < 8; ++rr) {
                    const int row = wv * 8 + rr;
                    row_dot(w2 + row * 256, lh4, ln, lds_gh, row);
                }
            } else if (wv < 6) {
                if (t + 1 < TT) {
                    const float4* ly4 = reinterpret_cast<const float4*>(lds_y[(t + 1) & 1]);
#pragma unroll
                    for (int rr = 0; rr < 8; ++rr) {
                        const int row = (wv - 3) * 8 + rr;
                        row_dot(w2 + (24 + row) * 256, ly4, ln, lds_gi[(t + 1) & 1], row);
                    }
                }
            } else {
                const int s = t + 2;
                if (s < TT) {
                    const int tl = tid - 384;   // 0..127
                    const u64* lr = y0log + (size_t)s * HDIM;
                    u64 v[8];
#pragma unroll
                    for (int k = 0; k < 8; ++k) v[k] = aload(lr + k * 128 + tl);
#pragma unroll
                    for (int k = 0; k < 8; ++k)
                        while ((unsigned)(v[k] >> 32) < (unsigned)(s + 1))
                            v[k] = aload(lr + k * 128 + tl);
#pragma unroll
                    for (int k = 0; k < 8; ++k)
                        lds_y[s & 1][k * 128 + tl] = __uint_as_float((unsigned)v[k]);
                }
            }
            __syncthreads();   // S1

            if (tid < 8) {
                const int u = u0 + tid;
                const float r = fsig(lds_gi[t & 1][tid]      + bi0 + lds_gh[tid]      + bh0);
                const float z = fsig(lds_gi[t & 1][8 + tid]  + bi1 + lds_gh[8 + tid]  + bh1);
                const float n = ftanh(lds_gi[t & 1][16 + tid] + bi2
                                      + r * (lds_gh[16 + tid] + bh2));
                const float h_new = (1.f - z) * n + z * h_own;
                h_own = h_new;
                pub_h(h1rep, (t + 1) & 1, u, pack_h((unsigned)(t + 1), h_new));
                out[(size_t)t * HDIM + u] = h_new;
                if (t == TT - 1) out[(size_t)TT * HDIM + HDIM + u] = h_new;
            }

            if (t + 1 < TT) {
                const unsigned need = (unsigned)(t + 1);
                const u64* hp = h1rep + ((size_t)xcd * 2 + ((t + 1) & 1)) * HDIM;
                u64 v0, v1;
                poll2(hp + 2 * tid, hp + 2 * tid + 1, need, v0, v1);
                float2 hv;
                hv.x = __uint_as_float((unsigned)v0);
                hv.y = __uint_as_float((unsigned)v1);
                reinterpret_cast<float2*>(lds_h)[tid] = hv;
            }
            __syncthreads();   // S2
        }
    }
}

// ---------------- launch ----------------
extern "C" void kernel_launch(void* const* d_in, const int* in_sizes, int n_in,
                              void* d_out, int out_size, void* d_ws, size_t ws_size,
                              hipStream_t stream) {
    const int*   idx = (const int*)d_in[0];
    const float* emb = (const float*)d_in[1];
    const float* wih = (const float*)d_in[2];
    const float* whh = (const float*)d_in[3];
    const float* bih = (const float*)d_in[4];
    const float* bhh = (const float*)d_in[5];
    float* out = (float*)d_out;

    float* x     = (float*)d_ws;                 // [T,H]
    float* gi    = x  + (size_t)TT * HDIM;       // [T,3H]
    u64*   y0log = (u64*)(gi + (size_t)TT * 3 * HDIM);   // [T][H] tagged
    u64*   h0rep = y0log + (size_t)TT * HDIM;            // [NREP][2][H]
    u64*   h1rep = h0rep + (size_t)NREP * 2 * HDIM;      // [NREP][2][H]
    size_t zero_bytes = ((size_t)TT * HDIM + 2 * (size_t)NREP * 2 * HDIM) * 8;

    hipMemsetAsync(y0log, 0, zero_bytes, stream);

    embed_kernel<<<TT, 256, 0, stream>>>(idx, emb, x);

    const size_t wstride = (size_t)3 * HDIM * HDIM;
    const size_t bstride = (size_t)3 * HDIM;

    gemm_nt_bias<<<dim3(TT / BM, 3 * HDIM / BN), 256, 0, stream>>>(
        x, wih, bih, gi, TT, 3 * HDIM, HDIM);

    gru_pipe<<<L0WG + L1WG, SBS, 0, stream>>>(
        gi, whh, bhh,
        wih + wstride, whh + wstride, bih + bstride, bhh + bstride,
        y0log, out, h0rep, h1rep);
}

// Round 15
// 10283.021 us; speedup vs baseline: 1.6653x; 1.6653x over previous
//
#include <hip/hip_runtime.h>
#include <hip/hip_bf16.h>

// v15 = v12 (best: 10.1ms) with ONE change: weights pre-converted to bf16 so
// each lane's slice is 16 uint4 = 64 VGPRs -> register-RESIDENT (f32 was 128
// VGPRs -> compiler rematerialized = per-step L2 stream). Dot = unpack
// (bflo/bfhi) + f32 fmaf, same 8-lane-slot + 3-shfl engine as v12.
// Exchange unchanged: 8-replica tagged h + poll2 + append-only y0 log.

#define TT    4096
#define HDIM  1024
#define L0WG  64
#define L1WG  128
#define SBS   512
#define NREP  8
typedef unsigned short ushort_t;
typedef unsigned long long u64;

// ---------------- embedding gather ----------------
__global__ void embed_kernel(const int* __restrict__ idx,
                             const float* __restrict__ emb,
                             float* __restrict__ x) {
    int t = blockIdx.x;
    int row = idx[t];
    const float4* src = reinterpret_cast<const float4*>(emb + (size_t)row * HDIM);
    float4* dst = reinterpret_cast<float4*>(x + (size_t)t * HDIM);
    dst[threadIdx.x] = src[threadIdx.x];
}

// ---------------- f32 -> bf16 (RNE) convert ----------------
__device__ __forceinline__ ushort_t f2bf(float f) {
    unsigned u = __float_as_uint(f);
    return (ushort_t)((u + 0x7FFFu + ((u >> 16) & 1u)) >> 16);
}
__global__ void conv_bf16(const float* __restrict__ w,
                          ushort_t* __restrict__ o, int n4) {
    int i = blockIdx.x * blockDim.x + threadIdx.x;
    if (i < n4) {
        float4 v = reinterpret_cast<const float4*>(w)[i];
        u64 r = (u64)f2bf(v.x) | ((u64)f2bf(v.y) << 16)
              | ((u64)f2bf(v.z) << 32) | ((u64)f2bf(v.w) << 48);
        reinterpret_cast<u64*>(o)[i] = r;
    }
}

// ---------------- fp32 NT GEMM (gi0) ----------------
#define BM 64
#define BN 64
#define BK 32
__global__ __launch_bounds__(256)
void gemm_nt_bias(const float* __restrict__ A,
                  const float* __restrict__ Bw,
                  const float* __restrict__ bias,
                  float* __restrict__ C,
                  int M, int N, int K) {
    __shared__ float As[BK][BM];
    __shared__ float Bs[BK][BN];
    const int tid = threadIdx.x;
    const int m0 = blockIdx.x * BM;
    const int n0 = blockIdx.y * BN;
    const int tx = tid & 15, ty = tid >> 4;
    const int lr = tid >> 3;
    const int lc = (tid & 7) * 4;

    float acc[4][4] = {};

    for (int k0 = 0; k0 < K; k0 += BK) {
#pragma unroll
        for (int pass = 0; pass < 2; ++pass) {
            int m = lr + pass * 32;
            float4 v = *reinterpret_cast<const float4*>(A + (size_t)(m0 + m) * K + k0 + lc);
            As[lc + 0][m] = v.x; As[lc + 1][m] = v.y;
            As[lc + 2][m] = v.z; As[lc + 3][m] = v.w;
            float4 u = *reinterpret_cast<const float4*>(Bw + (size_t)(n0 + m) * K + k0 + lc);
            Bs[lc + 0][m] = u.x; Bs[lc + 1][m] = u.y;
            Bs[lc + 2][m] = u.z; Bs[lc + 3][m] = u.w;
        }
        __syncthreads();
#pragma unroll
        for (int kk = 0; kk < BK; ++kk) {
            float4 a = *reinterpret_cast<const float4*>(&As[kk][ty * 4]);
            float4 b = *reinterpret_cast<const float4*>(&Bs[kk][tx * 4]);
            float av[4] = {a.x, a.y, a.z, a.w};
            float bv[4] = {b.x, b.y, b.z, b.w};
#pragma unroll
            for (int i = 0; i < 4; ++i)
#pragma unroll
                for (int j = 0; j < 4; ++j)
                    acc[i][j] = fmaf(av[i], bv[j], acc[i][j]);
        }
        __syncthreads();
    }

    float4 b4 = *reinterpret_cast<const float4*>(bias + n0 + tx * 4);
    float bb[4] = {b4.x, b4.y, b4.z, b4.w};
#pragma unroll
    for (int i = 0; i < 4; ++i) {
        int m = m0 + ty * 4 + i;
        float4 o;
        o.x = acc[i][0] + bb[0];
        o.y = acc[i][1] + bb[1];
        o.z = acc[i][2] + bb[2];
        o.w = acc[i][3] + bb[3];
        *reinterpret_cast<float4*>(C + (size_t)m * N + n0 + tx * 4) = o;
    }
}

// ---------------- helpers ----------------
__device__ __forceinline__ float fsig(float x) { return 1.f / (1.f + __expf(-x)); }
__device__ __forceinline__ float ftanh(float x) {
    return fmaf(-2.f, 1.f / (1.f + __expf(2.f * x)), 1.f);
}
__device__ __forceinline__ float bflo(unsigned u) { return __uint_as_float(u << 16); }
__device__ __forceinline__ float bfhi(unsigned u) { return __uint_as_float(u & 0xffff0000u); }
__device__ __forceinline__ u64 pack_h(unsigned seq, float h) {
    return ((u64)seq << 32) | (u64)__float_as_uint(h);
}
__device__ __forceinline__ u64 aload(const u64* p) {
    return __hip_atomic_load(p, __ATOMIC_RELAXED, __HIP_MEMORY_SCOPE_AGENT);
}
__device__ __forceinline__ u64 poll_h(const u64* p, unsigned need) {
    u64 v = aload(p);
    while ((unsigned)(v >> 32) < need) v = aload(p);
    return v;
}
__device__ __forceinline__ void poll2(const u64* p0, const u64* p1, unsigned need,
                                      u64& v0, u64& v1) {
    v0 = aload(p0);
    v1 = aload(p1);
    while ((unsigned)(v0 >> 32) < need || (unsigned)(v1 >> 32) < need) {
        v0 = aload(p0);
        v1 = aload(p1);
    }
}
__device__ __forceinline__ void pub_h(u64* rep, int par, int idx, u64 v) {
#pragma unroll
    for (int r = 0; r < NREP; ++r)
        __hip_atomic_store(rep + ((size_t)r * 2 + par) * HDIM + idx, v,
                           __ATOMIC_RELAXED, __HIP_MEMORY_SCOPE_AGENT);
}
// stage a full y-row from the tagged log into lds (lane l owns k*64+l)
__device__ __forceinline__ void stage_y(const u64* lrow, unsigned need,
                                        float* lds_y, int l) {
    u64 v[16];
#pragma unroll
    for (int k = 0; k < 16; ++k) v[k] = aload(lrow + k * 64 + l);
#pragma unroll
    for (int k = 0; k < 16; ++k)
        while ((unsigned)(v[k] >> 32) < need) v[k] = aload(lrow + k * 64 + l);
#pragma unroll
    for (int k = 0; k < 16; ++k)
        lds_y[k * 64 + l] = __uint_as_float((unsigned)v[k]);
}
// bf16-register row-slice dot against f32 LDS vector (8-lane slot, 3 shfl)
__device__ __forceinline__ float slice_dot(const uint4* Wb, const float4* v4, int l8) {
    float p = 0.f;
#pragma unroll
    for (int j = 0; j < 16; ++j) {
        const uint4 w = Wb[j];
        const float4 hA = v4[(j * 8 + l8) * 2];
        const float4 hB = v4[(j * 8 + l8) * 2 + 1];
        p = fmaf(bflo(w.x), hA.x, p); p = fmaf(bfhi(w.x), hA.y, p);
        p = fmaf(bflo(w.y), hA.z, p); p = fmaf(bfhi(w.y), hA.w, p);
        p = fmaf(bflo(w.z), hB.x, p); p = fmaf(bfhi(w.z), hB.y, p);
        p = fmaf(bflo(w.w), hB.z, p); p = fmaf(bfhi(w.w), hB.w, p);
    }
    p += __shfl_xor(p, 1);
    p += __shfl_xor(p, 2);
    p += __shfl_xor(p, 4);
    return p;
}

// ---------------- fused pipelined scan v15 ----------------
__global__ __launch_bounds__(SBS, 1)
void gru_pipe(const float* __restrict__ gi0,
              const ushort_t* __restrict__ wbh0,  // [3H][H] bf16
              const float* __restrict__ bhh0,
              const ushort_t* __restrict__ wbi1,  // [3H][H] bf16
              const ushort_t* __restrict__ wbh1,  // [3H][H] bf16
              const float* __restrict__ bih1,
              const float* __restrict__ bhh1,
              u64* y0log,                  // [T][HDIM] tagged, append-only
              float* __restrict__ out,     // [T*H + 2H]
              u64* h0rep, u64* h1rep) {    // [NREP][2][HDIM] tagged
    const int tid  = threadIdx.x;
    const int slot = tid >> 3;
    const int l8   = tid & 7;
    const int xcd  = blockIdx.x & 7;

    __shared__ float lds_h[HDIM];
    __shared__ float lds_y[HDIM];
    __shared__ float lds_gh[48];

    if (blockIdx.x < L0WG) {
        // ================= layer 0 (16 units/WG) =================
        const int g = blockIdx.x;

        // 64-VGPR bf16 weight slice (resident)
        uint4 Wb[16];
        if (slot < 48) {
            const int q = slot >> 4, jl = slot & 15;
            const uint4* row16 = reinterpret_cast<const uint4*>(
                wbh0 + (size_t)(q * HDIM + g * 16 + jl) * HDIM);
#pragma unroll
            for (int j = 0; j < 16; ++j) Wb[j] = row16[j * 8 + l8];
        } else {
#pragma unroll
            for (int j = 0; j < 16; ++j) Wb[j] = uint4{0, 0, 0, 0};
        }

        float bh0 = 0.f, bh1 = 0.f, bh2 = 0.f;
        float gir = 0.f, giz = 0.f, gin = 0.f;
        float h_own = 0.f;
        if (tid < 16) {
            const int gj = g * 16 + tid;
            bh0 = bhh0[0 * HDIM + gj];
            bh1 = bhh0[1 * HDIM + gj];
            bh2 = bhh0[2 * HDIM + gj];
            gir = gi0[gj];
            giz = gi0[HDIM + gj];
            gin = gi0[2 * HDIM + gj];
        }

        lds_h[tid] = 0.f;
        lds_h[tid + SBS] = 0.f;
        __syncthreads();

        const float4* lh4 = reinterpret_cast<const float4*>(lds_h);

        for (int t = 0; t < TT; ++t) {
            float nir = 0.f, niz = 0.f, nin = 0.f;
            if (tid < 16 && t + 1 < TT) {
                const float* base = gi0 + (size_t)(t + 1) * 3 * HDIM + g * 16 + tid;
                nir = base[0];
                niz = base[HDIM];
                nin = base[2 * HDIM];
            }

            if (slot < 48) {
                float p = slice_dot(Wb, lh4, l8);
                if (l8 == 0) lds_gh[slot] = p;
            }
            __syncthreads();   // S1

            if (tid < 16) {
                const int gj = g * 16 + tid;
                const float hr = lds_gh[tid]      + bh0;
                const float hz = lds_gh[16 + tid] + bh1;
                const float hn = lds_gh[32 + tid] + bh2;
                const float r = fsig(gir + hr);
                const float z = fsig(giz + hz);
                const float n = ftanh(gin + r * hn);
                const float h_new = (1.f - z) * n + z * h_own;
                h_own = h_new;
                const u64 pk = pack_h((unsigned)(t + 1), h_new);
                pub_h(h0rep, (t + 1) & 1, gj, pk);
                __hip_atomic_store(y0log + (size_t)t * HDIM + gj, pk,
                                   __ATOMIC_RELAXED, __HIP_MEMORY_SCOPE_AGENT);
                if (t == TT - 1) out[(size_t)TT * HDIM + gj] = h_new;
            }

            {
                const unsigned need = (unsigned)(t + 1);
                const u64* hp = h0rep + ((size_t)xcd * 2 + ((t + 1) & 1)) * HDIM;
                u64 v0, v1;
                poll2(hp + 2 * tid, hp + 2 * tid + 1, need, v0, v1);
                float2 hv;
                hv.x = __uint_as_float((unsigned)v0);
                hv.y = __uint_as_float((unsigned)v1);
                reinterpret_cast<float2*>(lds_h)[tid] = hv;
            }
            gir = nir; giz = niz; gin = nin;
            __syncthreads();   // S2
        }
    } else {
        // ================= layer 1 (8 units/WG) =================
        const int g1 = blockIdx.x - L0WG;

        // slots 0..23: whh1 rows; slots 24..47: wih1 rows (bf16, resident)
        uint4 Wb[16];
        if (slot < 48) {
            const int ss = (slot < 24) ? slot : slot - 24;
            const int q = ss >> 3, jl = ss & 7;
            const ushort_t* mat = (slot < 24) ? wbh1 : wbi1;
            const uint4* row16 = reinterpret_cast<const uint4*>(
                mat + (size_t)(q * HDIM + g1 * 8 + jl) * HDIM);
#pragma unroll
            for (int j = 0; j < 16; ++j) Wb[j] = row16[j * 8 + l8];
        } else {
#pragma unroll
            for (int j = 0; j < 16; ++j) Wb[j] = uint4{0, 0, 0, 0};
        }

        float bh0 = 0.f, bh1 = 0.f, bh2 = 0.f;
        float bi0 = 0.f, bi1 = 0.f, bi2 = 0.f;
        float h_own = 0.f;
        if (tid < 8) {
            const int u = g1 * 8 + tid;
            bh0 = bhh1[0 * HDIM + u];
            bh1 = bhh1[1 * HDIM + u];
            bh2 = bhh1[2 * HDIM + u];
            bi0 = bih1[0 * HDIM + u];
            bi1 = bih1[1 * HDIM + u];
            bi2 = bih1[2 * HDIM + u];
        }

        lds_h[tid] = 0.f;
        lds_h[tid + SBS] = 0.f;
        // prologue: stage y(0) from the tagged log (wave 7)
        if (tid >= 448) {
            stage_y(y0log, 1u, lds_y, tid - 448);
        }
        __syncthreads();

        const float4* lh4 = reinterpret_cast<const float4*>(lds_h);
        const float4* ly4 = reinterpret_cast<const float4*>(lds_y);

        for (int t = 0; t < TT; ++t) {
            if (slot < 48) {
                const float4* s4 = (slot < 24) ? lh4 : ly4;
                float p = slice_dot(Wb, s4, l8);
                if (l8 == 0) lds_gh[slot] = p;
            }
            __syncthreads();   // S1

            if (tid < 8) {
                const int u = g1 * 8 + tid;
                const float hr = lds_gh[tid]      + bh0;
                const float hz = lds_gh[8 + tid]  + bh1;
                const float hn = lds_gh[16 + tid] + bh2;
                const float ir = lds_gh[24 + tid] + bi0;
                const float iz = lds_gh[32 + tid] + bi1;
                const float in_ = lds_gh[40 + tid] + bi2;
                const float r = fsig(ir + hr);
                const float z = fsig(iz + hz);
                const float n = ftanh(in_ + r * hn);
                const float h_new = (1.f - z) * n + z * h_own;
                h_own = h_new;
                pub_h(h1rep, (t + 1) & 1, u, pack_h((unsigned)(t + 1), h_new));
                out[(size_t)t * HDIM + u] = h_new;
                if (t == TT - 1) out[(size_t)TT * HDIM + HDIM + u] = h_new;
            }

            // wave 7: stage y(t+1) from the tagged log
            if (tid >= 448 && t + 1 < TT) {
                stage_y(y0log + (size_t)(t + 1) * HDIM, (unsigned)(t + 2),
                        lds_y, tid - 448);
            }

            {
                const unsigned need = (unsigned)(t + 1);
                const u64* hp = h1rep + ((size_t)xcd * 2 + ((t + 1) & 1)) * HDIM;
                u64 v0, v1;
                poll2(hp + 2 * tid, hp + 2 * tid + 1, need, v0, v1);
                float2 hv;
                hv.x = __uint_as_float((unsigned)v0);
                hv.y = __uint_as_float((unsigned)v1);
                reinterpret_cast<float2*>(lds_h)[tid] = hv;
            }
            __syncthreads();   // S2
        }
    }
}

// ---------------- launch ----------------
extern "C" void kernel_launch(void* const* d_in, const int* in_sizes, int n_in,
                              void* d_out, int out_size, void* d_ws, size_t ws_size,
                              hipStream_t stream) {
    const int*   idx = (const int*)d_in[0];
    const float* emb = (const float*)d_in[1];
    const float* wih = (const float*)d_in[2];
    const float* whh = (const float*)d_in[3];
    const float* bih = (const float*)d_in[4];
    const float* bhh = (const float*)d_in[5];
    float* out = (float*)d_out;

    float* x     = (float*)d_ws;                 // [T,H]
    float* gi    = x  + (size_t)TT * HDIM;       // [T,3H]
    u64*   y0log = (u64*)(gi + (size_t)TT * 3 * HDIM);   // [T][H] tagged
    u64*   h0rep = y0log + (size_t)TT * HDIM;            // [NREP][2][H]
    u64*   h1rep = h0rep + (size_t)NREP * 2 * HDIM;      // [NREP][2][H]
    ushort_t* wbh0 = (ushort_t*)(h1rep + (size_t)NREP * 2 * HDIM);  // [3H*H]
    ushort_t* wbh1 = wbh0 + (size_t)3 * HDIM * HDIM;                // [3H*H]
    ushort_t* wbi1 = wbh1 + (size_t)3 * HDIM * HDIM;                // [3H*H]
    size_t zero_bytes = ((size_t)TT * HDIM + 2 * (size_t)NREP * 2 * HDIM) * 8;

    hipMemsetAsync(y0log, 0, zero_bytes, stream);

    embed_kernel<<<TT, 256, 0, stream>>>(idx, emb, x);

    const size_t wstride = (size_t)3 * HDIM * HDIM;
    const size_t bstride = (size_t)3 * HDIM;

    // bf16 weight copies (one-time, ~19MB total)
    const int n4 = 3 * HDIM * HDIM / 4;
    conv_bf16<<<(n4 + 255) / 256, 256, 0, stream>>>(whh, wbh0, n4);
    conv_bf16<<<(n4 + 255) / 256, 256, 0, stream>>>(whh + wstride, wbh1, n4);
    conv_bf16<<<(n4 + 255) / 256, 256, 0, stream>>>(wih + wstride, wbi1, n4);

    gemm_nt_bias<<<dim3(TT / BM, 3 * HDIM / BN), 256, 0, stream>>>(
        x, wih, bih, gi, TT, 3 * HDIM, HDIM);

    gru_pipe<<<L0WG + L1WG, SBS, 0, stream>>>(
        gi, wbh0, bhh,
        wbi1, wbh1, bih + bstride, bhh + bstride,
        y0log, out, h0rep, h1rep);
}